// Round 2
// baseline (921.652 us; speedup 1.0000x reference)
//
#include <hip/hip_runtime.h>
#include <cmath>

#define THREADS 256

struct Tables { float cont[12]; float cw[12]; float ew[12]; };

static Tables make_tables() {
    Tables tb;
    tb.cont[0] = 0.0f;
    for (int j = 1; j < 12; j++) {
        // numpy: x = linspace(0, b, 2000) (step b/1999), dx = b/2000
        double b = (double)j;
        double s = 0.0;
        for (int k = 0; k < 2000; k++) {
            double x = b * (double)k / 1999.0;
            s += pow(0.8, x);
        }
        double integ = s * (b / 2000.0);
        tb.cont[j] = (float)(1.0 / integ);
    }
    for (int s = 0; s < 12; s++) {
        double w = pow(0.8, (double)s);
        tb.cw[s] = (float)w;
        tb.ew[s] = (float)(w + 1.0);
    }
    return tb;
}

__global__ void zero_acc(double* g) {
    int t = threadIdx.x;
    if (t < 5) g[t] = 0.0;
    if (t == 5) *(unsigned int*)(g + 8) = 0u;   // ticket counter @ byte 64
}

__global__ __launch_bounds__(THREADS) void loss_fused(
    const float* __restrict__ geo,   // (B,12,33)
    const float* __restrict__ mgo,   // (B,13,33)
    const int*   __restrict__ pos,   // (B,13)
    const int*   __restrict__ mgt,   // (B,13)
    const float* __restrict__ aux,
    const float* __restrict__ taux,
    const float* __restrict__ sigma,
    float*       __restrict__ out,
    double*      __restrict__ gacc,  // 5 doubles
    unsigned int* __restrict__ counter,
    int B, int geoBlocks, int totalBlocks, Tables tb)
{
    const int t = threadIdx.x;
    float v0 = 0.0f, v1 = 0.0f, v2 = 0.0f;
    const bool isGeo = (blockIdx.x < (unsigned)geoBlocks);

    if (isGeo) {
        // one thread per row: all per-row coupling (argmin/prefix) is thread-local
        int row = blockIdx.x * THREADS + t;
        if (row < B) {
            const float* xr = geo + (long long)row * 396;
            const int*   pr = pos + (long long)row * 13 + 1;
            float pssum = 0.0f, cs = 0.0f, es = 0.0f;
            int mi = -1;   // first-incorrect index, -1 = none yet
            for (int s = 0; s < 12; s++) {
                const float* xs = xr + s * 33;
                float xv[33];
                #pragma unroll
                for (int k = 0; k < 33; k++) xv[k] = xs[k];
                float m = xv[0]; int am = 0;
                #pragma unroll
                for (int k = 1; k < 33; k++) { if (xv[k] > m) { m = xv[k]; am = k; } }
                float sum = 0.0f;
                #pragma unroll
                for (int k = 0; k < 33; k++) sum += __expf(xv[k] - m);
                float lse = __logf(sum) + m;
                int tg = pr[s];
                int tc = tg < 0 ? 0 : (tg > 32 ? 32 : tg);
                float ce = (tg == 32) ? 0.0f : (lse - xv[tc]);  // ignore_index = 32
                bool corr = (am == tg);
                if (corr) cs += ce * tb.cw[s]; else es += ce * tb.ew[s];
                if (mi < 0) { if (corr) pssum += ce; else mi = s; }
            }
            if (mi < 0) { pssum = 0.0f; mi = 0; }  // all-correct: argmin=0, cont=0
            v0 = pssum * tb.cont[mi];
            v1 = cs;
            v2 = es;
        }
    } else {
        // one thread per (b,s) mask-CE task
        long long task = (long long)(blockIdx.x - geoBlocks) * THREADS + t;
        if (task < (long long)B * 13) {
            int tg = mgt[task];
            const float* xs = mgo + task * 33;
            float xv[33];
            #pragma unroll
            for (int k = 0; k < 33; k++) xv[k] = xs[k];
            float m = xv[0];
            #pragma unroll
            for (int k = 1; k < 33; k++) m = fmaxf(m, xv[k]);
            float sum = 0.0f;
            #pragma unroll
            for (int k = 0; k < 33; k++) sum += __expf(xv[k] - m);
            float lse = __logf(sum) + m;
            int tc = tg < 0 ? 0 : (tg > 32 ? 32 : tg);
            if (tg != -100) { v0 = lse - xv[tc]; v1 = 1.0f; }
        }
    }

    // block reduction: wave64 shuffle, then cross-wave via LDS (no LDS atomics)
    #pragma unroll
    for (int off = 32; off; off >>= 1) {
        v0 += __shfl_down(v0, off, 64);
        v1 += __shfl_down(v1, off, 64);
        v2 += __shfl_down(v2, off, 64);
    }
    __shared__ float red[4][3];
    const int wid = t >> 6, lane = t & 63;
    if (lane == 0) { red[wid][0] = v0; red[wid][1] = v1; red[wid][2] = v2; }
    __syncthreads();
    if (t == 0) {
        float a0 = 0, a1 = 0, a2 = 0;
        for (int w = 0; w < 4; w++) { a0 += red[w][0]; a1 += red[w][1]; a2 += red[w][2]; }
        if (isGeo) {
            atomicAdd(&gacc[2], (double)a0);
            atomicAdd(&gacc[3], (double)a1);
            atomicAdd(&gacc[4], (double)a2);
        } else {
            atomicAdd(&gacc[0], (double)a0);
            atomicAdd(&gacc[1], (double)a1);
        }
        __threadfence();
        unsigned int old = atomicAdd(counter, 1u);
        if (old == (unsigned)(totalBlocks - 1)) {
            // last block finalizes; read accumulators via device-scope atomics
            double g[5];
            for (int i = 0; i < 5; i++) g[i] = atomicAdd(&gacc[i], 0.0);
            double denom = (double)B * 12.0;
            double mask_loss = g[0] / fmax(g[1], 1.0);
            double prefix = g[2] / denom, corrL = g[3] / denom, errL = g[4] / denom;
            double geoL = prefix + corrL + errL;
            double L[4] = { geoL, mask_loss, (double)aux[0], (double)taux[0] };
            double wsum = 0.0, prod = 1.0;
            for (int i = 0; i < 4; i++) {
                double sg = (double)sigma[i];
                wsum += 0.5 * L[i] / (sg * sg);
                prod *= sg;
            }
            wsum += log(prod);
            out[0] = (float)wsum;
            out[1] = (float)prefix;
            out[2] = (float)corrL;
            out[3] = (float)errL;
            out[4] = (float)mask_loss;
        }
    }
}

extern "C" void kernel_launch(void* const* d_in, const int* in_sizes, int n_in,
                              void* d_out, int out_size, void* d_ws, size_t ws_size,
                              hipStream_t stream)
{
    static Tables tb = make_tables();   // host-only, graph-capture safe

    const float* geo   = (const float*)d_in[0];
    const float* mgo   = (const float*)d_in[1];
    const int*   pos   = (const int*)d_in[2];
    const int*   mgt   = (const int*)d_in[3];
    const float* aux   = (const float*)d_in[4];
    const float* taux  = (const float*)d_in[5];
    const float* sigma = (const float*)d_in[6];
    float* out = (float*)d_out;

    int B = in_sizes[2] / 13;
    double* gacc = (double*)d_ws;
    unsigned int* counter = (unsigned int*)((char*)d_ws + 64);

    int geoBlocks  = (B + THREADS - 1) / THREADS;
    long long maskTasks = (long long)B * 13;
    int maskBlocks = (int)((maskTasks + THREADS - 1) / THREADS);
    int totalBlocks = geoBlocks + maskBlocks;

    hipLaunchKernelGGL(zero_acc, dim3(1), dim3(64), 0, stream, gacc);
    hipLaunchKernelGGL(loss_fused, dim3(totalBlocks), dim3(THREADS), 0, stream,
                       geo, mgo, pos, mgt, aux, taux, sigma, out,
                       gacc, counter, B, geoBlocks, totalBlocks, tb);
}

// Round 3
// 448.312 us; speedup vs baseline: 2.0558x; 2.0558x over previous
//
#include <hip/hip_runtime.h>
#include <cmath>

#define THREADS 256
#define MTASKS  224   // mask (b,s) tasks per block: 224*132B = 29568 B LDS
#define GROWS   18    // geo rows per block: 18*1584B = 28512 B LDS
#define SLOTS   64    // accumulator spreading to avoid same-address atomic serialization

struct Tables { float cont[13]; float cw[12]; float ew[12]; };

static Tables make_tables() {
    Tables tb;
    tb.cont[0] = 0.0f;
    for (int j = 1; j <= 12; j++) {
        // numpy: x = linspace(0, b, 2000) (step b/1999), dx = b/2000
        double b = (double)j;
        double s = 0.0;
        for (int k = 0; k < 2000; k++) {
            double x = b * (double)k / 1999.0;
            s += pow(0.8, x);
        }
        double integ = s * (b / 2000.0);
        tb.cont[j] = (float)(1.0 / integ);
    }
    for (int s = 0; s < 12; s++) {
        double w = pow(0.8, (double)s);
        tb.cw[s] = (float)w;
        tb.ew[s] = (float)(w + 1.0);
    }
    return tb;
}

__global__ void zero_acc(double* g) {
    int t = threadIdx.x;
    if (t < 5 * SLOTS) g[t] = 0.0;
}

__global__ __launch_bounds__(THREADS) void loss_fused(
    const float* __restrict__ geo,   // (B,12,33)
    const float* __restrict__ mgo,   // (B,13,33)
    const int*   __restrict__ pos,   // (B,13)
    const int*   __restrict__ mgt,   // (B,13)
    double*      __restrict__ gacc,  // 5 * SLOTS doubles
    int B, int geoBlocks, Tables tb)
{
    __shared__ float buf[7392];            // 29568 B, fits both block types
    __shared__ float s_ce[GROWS * 12];
    __shared__ int   s_corr[GROWS * 12];
    __shared__ float sh_cont[13];
    __shared__ float sh_cw[12];
    __shared__ float sh_ew[12];
    __shared__ float red[4][3];

    const int t = threadIdx.x;
    float v0 = 0.0f, v1 = 0.0f, v2 = 0.0f;
    const bool isGeo = (blockIdx.x < (unsigned)geoBlocks);

    if (isGeo) {
        // copy tables to LDS with STATIC indices only (dynamic kernarg index would spill)
        if (t == 0) {
            #pragma unroll
            for (int j = 0; j < 13; j++) sh_cont[j] = tb.cont[j];
            #pragma unroll
            for (int j = 0; j < 12; j++) { sh_cw[j] = tb.cw[j]; sh_ew[j] = tb.ew[j]; }
        }
        const long long row0 = (long long)blockIdx.x * GROWS;
        const int nrows = min(GROWS, (int)(B - row0));
        {   // stage nrows*396 floats, fully coalesced float4 (1584 B/row, 16B-aligned)
            const float4* src4 = reinterpret_cast<const float4*>(geo + row0 * 396);
            float4* dst4 = reinterpret_cast<float4*>(buf);
            const int nf4 = (nrows * 396) >> 2;   // 396 divisible by 4
            for (int i = t; i < nf4; i += THREADS) dst4[i] = src4[i];
        }
        __syncthreads();

        const int ntask = nrows * 12;
        if (t < ntask) {
            const int r = t / 12, s = t - r * 12;
            const float* x = buf + r * 396 + s * 33;
            float xv[33];
            #pragma unroll
            for (int k = 0; k < 33; k++) xv[k] = x[k];   // static idx -> registers
            float m = xv[0]; int am = 0;
            #pragma unroll
            for (int k = 1; k < 33; k++) { if (xv[k] > m) { m = xv[k]; am = k; } }
            float sum = 0.0f;
            #pragma unroll
            for (int k = 0; k < 33; k++) sum += __expf(xv[k] - m);
            float lse = __logf(sum) + m;
            int tg = pos[(row0 + r) * 13 + s + 1];
            int tc = tg < 0 ? 0 : (tg > 32 ? 32 : tg);
            float xtc = 0.0f;
            #pragma unroll
            for (int k = 0; k < 33; k++) { if (k == tc) xtc = xv[k]; }  // predicated, no spill
            float ce = (tg == 32) ? 0.0f : (lse - xtc);   // ignore_index = 32
            bool corr = (am == tg);
            v1 = corr ? ce * sh_cw[s] : 0.0f;
            v2 = corr ? 0.0f : ce * sh_ew[s];
            s_ce[t] = ce;
            s_corr[t] = corr ? 1 : 0;
        }
        __syncthreads();

        // per-row prefix: first-incorrect index + weighted prefix sum
        if (t < nrows) {
            float ps = 0.0f; int mi = 12;
            for (int s = 0; s < 12; s++) {
                if (!s_corr[t * 12 + s]) { mi = s; break; }
                ps += s_ce[t * 12 + s];
            }
            v0 = (mi >= 12) ? 0.0f : ps * sh_cont[mi];   // all-correct: cont idx 0 -> 0
        }
    } else {
        const long long totalTasks = (long long)B * 13;
        const long long base = (long long)(blockIdx.x - geoBlocks) * MTASKS;
        const int cnt = (int)min((long long)MTASKS, totalTasks - base);
        {   // stage cnt*33 floats (base byte = base*132, 16B-aligned since base%224==0 -> *132 %16==0)
            const float* src = mgo + base * 33;
            const int nf = cnt * 33, nf4 = nf >> 2;
            const float4* src4 = reinterpret_cast<const float4*>(src);
            float4* dst4 = reinterpret_cast<float4*>(buf);
            for (int i = t; i < nf4; i += THREADS) dst4[i] = src4[i];
            for (int i = (nf4 << 2) + t; i < nf; i += THREADS) buf[i] = src[i];
        }
        __syncthreads();

        if (t < cnt) {
            const float* x = buf + t * 33;
            float xv[33];
            #pragma unroll
            for (int k = 0; k < 33; k++) xv[k] = x[k];
            float m = xv[0];
            #pragma unroll
            for (int k = 1; k < 33; k++) m = fmaxf(m, xv[k]);
            float sum = 0.0f;
            #pragma unroll
            for (int k = 0; k < 33; k++) sum += __expf(xv[k] - m);
            float lse = __logf(sum) + m;
            int tg = mgt[base + t];
            int tc = tg < 0 ? 0 : (tg > 32 ? 32 : tg);
            float xtc = 0.0f;
            #pragma unroll
            for (int k = 0; k < 33; k++) { if (k == tc) xtc = xv[k]; }
            if (tg != -100) { v0 = lse - xtc; v1 = 1.0f; }
        }
    }

    // block reduction: wave64 shuffle then cross-wave via LDS
    #pragma unroll
    for (int off = 32; off; off >>= 1) {
        v0 += __shfl_down(v0, off, 64);
        v1 += __shfl_down(v1, off, 64);
        v2 += __shfl_down(v2, off, 64);
    }
    const int wid = t >> 6, lane = t & 63;
    if (lane == 0) { red[wid][0] = v0; red[wid][1] = v1; red[wid][2] = v2; }
    __syncthreads();
    if (t == 0) {
        float a0 = 0, a1 = 0, a2 = 0;
        for (int w = 0; w < 4; w++) { a0 += red[w][0]; a1 += red[w][1]; a2 += red[w][2]; }
        const int slot = blockIdx.x & (SLOTS - 1);
        if (isGeo) {
            atomicAdd(&gacc[2 * SLOTS + slot], (double)a0);
            atomicAdd(&gacc[3 * SLOTS + slot], (double)a1);
            atomicAdd(&gacc[4 * SLOTS + slot], (double)a2);
        } else {
            atomicAdd(&gacc[0 * SLOTS + slot], (double)a0);
            atomicAdd(&gacc[1 * SLOTS + slot], (double)a1);
        }
    }
}

__global__ void finalize(const double* __restrict__ g,
                         const float* __restrict__ aux,
                         const float* __restrict__ taux,
                         const float* __restrict__ sigma,
                         float* __restrict__ out, double denom)
{
    const int i = threadIdx.x;   // 64 threads
    double a[5];
    #pragma unroll
    for (int q = 0; q < 5; q++) a[q] = g[q * SLOTS + i];
    #pragma unroll
    for (int off = 32; off; off >>= 1) {
        #pragma unroll
        for (int q = 0; q < 5; q++) a[q] += __shfl_down(a[q], off, 64);
    }
    if (i == 0) {
        double mask_loss = a[0] / fmax(a[1], 1.0);
        double prefix = a[2] / denom, corrL = a[3] / denom, errL = a[4] / denom;
        double geoL = prefix + corrL + errL;
        double L[4] = { geoL, mask_loss, (double)aux[0], (double)taux[0] };
        double wsum = 0.0, prod = 1.0;
        for (int q = 0; q < 4; q++) {
            double sg = (double)sigma[q];
            wsum += 0.5 * L[q] / (sg * sg);
            prod *= sg;
        }
        wsum += log(prod);
        out[0] = (float)wsum;
        out[1] = (float)prefix;
        out[2] = (float)corrL;
        out[3] = (float)errL;
        out[4] = (float)mask_loss;
    }
}

extern "C" void kernel_launch(void* const* d_in, const int* in_sizes, int n_in,
                              void* d_out, int out_size, void* d_ws, size_t ws_size,
                              hipStream_t stream)
{
    static Tables tb = make_tables();   // host-only, graph-capture safe

    const float* geo   = (const float*)d_in[0];
    const float* mgo   = (const float*)d_in[1];
    const int*   pos   = (const int*)d_in[2];
    const int*   mgt   = (const int*)d_in[3];
    const float* aux   = (const float*)d_in[4];
    const float* taux  = (const float*)d_in[5];
    const float* sigma = (const float*)d_in[6];
    float* out = (float*)d_out;

    const int B = in_sizes[2] / 13;
    double* gacc = (double*)d_ws;   // 5*SLOTS doubles = 2560 B

    const int geoBlocks  = (B + GROWS - 1) / GROWS;
    const long long maskTasks = (long long)B * 13;
    const int maskBlocks = (int)((maskTasks + MTASKS - 1) / MTASKS);
    const int totalBlocks = geoBlocks + maskBlocks;

    hipLaunchKernelGGL(zero_acc, dim3(1), dim3(512), 0, stream, gacc);
    hipLaunchKernelGGL(loss_fused, dim3(totalBlocks), dim3(THREADS), 0, stream,
                       geo, mgo, pos, mgt, gacc, B, geoBlocks, tb);
    hipLaunchKernelGGL(finalize, dim3(1), dim3(64), 0, stream,
                       gacc, aux, taux, sigma, out, (double)B * 12.0);
}